// Round 7
// baseline (344.985 us; speedup 1.0000x reference)
//
#include <hip/hip_runtime.h>
#include <stdint.h>

typedef __attribute__((ext_vector_type(8))) short short8;
typedef __attribute__((ext_vector_type(4))) short short4v;
typedef __attribute__((ext_vector_type(4))) float floatx4;
typedef __attribute__((ext_vector_type(4))) _Float16 half4;
typedef __attribute__((ext_vector_type(2))) __fp16 pk2;

#define SEQ 2048
#define NTOK 8192
// 0.25 * log2(e): folds the 1/sqrt(H) quirk-scale and exp->exp2 into Q proj.
#define QSCALE 0.360673760222241f

#define MFMA16F16(a,b,c) __builtin_amdgcn_mfma_f32_16x16x16f16((a),(b),(c),0,0,0)

__device__ __forceinline__ float b2f(unsigned short u){
  union { unsigned int i; float f; } v; v.i = ((unsigned int)u) << 16; return v.f;
}
__device__ __forceinline__ unsigned short f2b(float f){
  union { float f; unsigned int i; } v; v.f = f;
  unsigned int r = v.i + 0x7fffu + ((v.i >> 16) & 1u);
  return (unsigned short)(r >> 16);
}
// async global->LDS, 16B per lane. Dest = wave-uniform base + lane*16.
__device__ __forceinline__ void async16(const unsigned short* g, unsigned short* l){
  __builtin_amdgcn_global_load_lds(
      (const __attribute__((address_space(1))) unsigned int*)g,
      (__attribute__((address_space(3))) unsigned int*)l, 16, 0, 0);
}

// ---------- fused prep: convert_x | transpose_w | bias_concat --------------
__global__ __launch_bounds__(256) void prep_kernel(
    const float* __restrict__ x,
    const float* __restrict__ wq, const float* __restrict__ wk,
    const float* __restrict__ wv, const float* __restrict__ wo,
    const float* __restrict__ bq, const float* __restrict__ bk,
    const float* __restrict__ bv,
    unsigned short* __restrict__ xb,
    unsigned short* __restrict__ wqkvT, unsigned short* __restrict__ woT,
    float* __restrict__ bqkv)
{
  __shared__ unsigned short lT[64][72];
  const int bid = blockIdx.x;
  const int tid = threadIdx.x;
  if (bid < 8192){
    int i = (bid*256 + tid)*4;
    float4 v = *(const float4*)(x + i);
    short4v o;
    o[0] = (short)f2b(v.x); o[1] = (short)f2b(v.y);
    o[2] = (short)f2b(v.z); o[3] = (short)f2b(v.w);
    *(short4v*)(xb + i) = o;
  } else if (bid < 9216){
    int idx = bid - 8192;
    int sel = idx >> 8, rest = idx & 255;
    const float* src = (sel==0)?wq:(sel==1)?wk:(sel==2)?wv:wo;
    unsigned short* dst = (sel<3) ? (wqkvT + (size_t)sel*1024*1024) : woT;
    int n0 = (rest & 15) * 64, k0 = (rest >> 4) * 64;
#pragma unroll
    for (int i=0;i<4;i++){
      int ch = tid + i*256;
      int r = ch>>4, c = (ch&15)*4;
      float4 v = *(const float4*)(src + (size_t)(k0+r)*1024 + n0 + c);
      lT[r][c+0] = f2b(v.x); lT[r][c+1] = f2b(v.y);
      lT[r][c+2] = f2b(v.z); lT[r][c+3] = f2b(v.w);
    }
    __syncthreads();
#pragma unroll
    for (int i=0;i<2;i++){
      int ch = tid + i*256;
      int rn = ch>>3, c = (ch&7)*8;
      short8 v;
#pragma unroll
      for (int j=0;j<8;j++) v[j] = (short)lT[c+j][rn];
      *(short8*)(dst + (size_t)(n0+rn)*1024 + k0 + c) = v;
    }
  } else {
    int i = (bid - 9216)*256 + tid;
    if (i < 3072){
      int sel = i >> 10, j = i & 1023;
      bqkv[i] = (sel==0)?bq[j]:(sel==1)?bk[j]:bv[j];
    }
  }
}

// ---------------- GEMM: C(MxN) = A(MxK) @ Bt(NxK)^T + bias ----------------
// OUT_MODE: 0 = bf16 store, 2 = f32 atomicAdd (split-K; bias only from z==0).
// SCALE_Q: (acc+bias)*QSCALE for cols<1024 (Q columns).
template<int OUT_MODE, int SCALE_Q>
__global__ __launch_bounds__(256) void gemm_bt_kernel(
    const unsigned short* __restrict__ A,
    const unsigned short* __restrict__ Bt,
    const float* __restrict__ bias,
    void* __restrict__ Cv,
    int M, int N, int K, int Klen)
{
  __shared__ unsigned short lA[128*64];
  __shared__ unsigned short lB[128*64];
  const int tid  = threadIdx.x;
  const int lane = tid & 63;
  const int wave = tid >> 6;
  const int quad = lane >> 4;
  const int l15  = lane & 15;
  const int wR = (wave >> 1) * 64;
  const int wC = (wave & 1) * 64;
  const int rowB = blockIdx.y * 128;
  const int colB = blockIdx.x * 128;
  const int kt0  = blockIdx.z * Klen;

  const int srow = wave*32 + (lane>>3);
  const int sc8  = (lane&7) ^ (lane>>3);
  const unsigned short* gA = A  + (size_t)(rowB + srow)*K + sc8*8;
  const unsigned short* gB = Bt + (size_t)(colB + srow)*K + sc8*8;
  unsigned short* lAw = lA + wave*32*64 + lane*8;
  unsigned short* lBw = lB + wave*32*64 + lane*8;

  floatx4 acc[4][4];
#pragma unroll
  for (int t=0;t<4;t++)
#pragma unroll
    for (int u=0;u<4;u++) acc[t][u] = (floatx4){0.f,0.f,0.f,0.f};

  for (int kt = kt0; kt < kt0 + Klen; kt += 64){
    __syncthreads();
#pragma unroll
    for (int i=0;i<4;i++){
      async16(gA + (size_t)i*8*K + kt, lAw + i*512);
      async16(gB + (size_t)i*8*K + kt, lBw + i*512);
    }
    __syncthreads();
#pragma unroll
    for (int ks=0; ks<2; ks++){
      const int cph = ((ks*4 + quad) ^ (l15 & 7)) * 8;
      short8 af[4], bf[4];
#pragma unroll
      for (int t=0;t<4;t++) af[t] = *(const short8*)&lA[(wR + t*16 + l15)*64 + cph];
#pragma unroll
      for (int u=0;u<4;u++) bf[u] = *(const short8*)&lB[(wC + u*16 + l15)*64 + cph];
#pragma unroll
      for (int t=0;t<4;t++)
#pragma unroll
        for (int u=0;u<4;u++)
          acc[t][u] = __builtin_amdgcn_mfma_f32_16x16x32_bf16(af[t], bf[u], acc[t][u], 0, 0, 0);
    }
  }
#pragma unroll
  for (int u=0;u<4;u++){
    int col = colB + wC + u*16 + l15;
    float bval = (OUT_MODE == 2 && blockIdx.z != 0) ? 0.f : bias[col];
    float scale = (SCALE_Q && col < 1024) ? QSCALE : 1.0f;
#pragma unroll
    for (int t=0;t<4;t++){
      int row0 = rowB + wR + t*16 + quad*4;
#pragma unroll
      for (int r=0;r<4;r++){
        float val = (acc[t][u][r] + bval) * scale;
        if (OUT_MODE == 2)      atomicAdd(&((float*)Cv)[(size_t)(row0 + r)*N + col], val);
        else ((unsigned short*)Cv)[(size_t)(row0 + r)*N + col] = f2b(val);
      }
    }
  }
}

// ------ V transpose+convert: qkv V-cols (bf16) -> Vt f16 [(bh*64+dv)][s] ---
__global__ __launch_bounds__(256) void transpose_v_kernel(
    const unsigned short* __restrict__ qkv,
    unsigned short* __restrict__ vt)   // f16 bits
{
  __shared__ unsigned short lT[64][72];
  const int bh = blockIdx.x;
  const int b = bh >> 4, h = bh & 15;
  const int s0 = blockIdx.y * 64;
  const int tid = threadIdx.x;
#pragma unroll
  for (int i=0;i<2;i++){
    int ch = tid + i*256;
    int r = ch >> 3, c = (ch & 7)*8;
    short8 raw = *(const short8*)(qkv + (size_t)(b*SEQ + s0 + r)*3072 + 2048 + h*64 + c);
#pragma unroll
    for (int j=0;j<8;j++){
      union { _Float16 h; unsigned short u; } cv;
      cv.h = (_Float16)b2f((unsigned short)raw[j]);
      lT[r][c+j] = cv.u;
    }
  }
  __syncthreads();
#pragma unroll
  for (int i=0;i<2;i++){
    int ch = tid + i*256;
    int dv = ch >> 3, c = (ch & 7)*8;
    short8 v;
#pragma unroll
    for (int j=0;j<8;j++) v[j] = (short)lT[c+j][dv];
    *(short8*)(vt + (size_t)(bh*64 + dv)*2048 + s0 + c) = v;
  }
}

// ---------------- flash attention forward, S^T formulation -----------------
// R4 base (best measured): 2-barrier register-prefetch staging, stride-72
// padded LDS for BOTH tiles (b128 reads land 2-way aliased = free).
// V staged with column permutation s=(u*16+quad*4+j) -> (quad*16+u*4+j) so
// each PV B-fragment pair loads as ONE ds_read_b128 (was 4x b64, 4-way
// conflicted — the R4 conflict source).
__global__ __launch_bounds__(256) void flash_attn_kernel(
    const unsigned short* __restrict__ qkv,
    const unsigned short* __restrict__ vt,      // f16 bits
    unsigned short* __restrict__ attn_out)      // bf16
{
  __shared__ unsigned short sK[64][72];         // bf16
  __shared__ unsigned short sVt[64][72];        // f16 bits, sigma-permuted cols
  const int bh = blockIdx.x;
  const int b = bh >> 4, h = bh & 15;
  const int qt = blockIdx.y;
  const int tid = threadIdx.x;
  const int wave = tid >> 6;
  const int lane = tid & 63;
  const int quad = lane >> 4, l15 = lane & 15;
  const int tok0 = b*SEQ + qt*128;

  // Q B-fragments straight from global (n = q = l15, k contiguous)
  short8 qf[2][2];
#pragma unroll
  for (int t=0;t<2;t++)
#pragma unroll
    for (int ks=0;ks<2;ks++)
      qf[t][ks] = *(const short8*)(qkv + (size_t)(tok0 + wave*32 + t*16 + l15)*3072
                                   + h*64 + ks*32 + quad*8);

  floatx4 oacc[2][4];
  float psum[2] = {0.f, 0.f};
#pragma unroll
  for (int t=0;t<2;t++)
#pragma unroll
    for (int v=0;v<4;v++) oacc[t][v] = (floatx4){0.f,0.f,0.f,0.f};

  const int ch0 = tid, ch1 = tid + 256;
  const int r0 = ch0 >> 3, c0 = (ch0 & 7)*8;
  const int r1 = ch1 >> 3, c1 = (ch1 & 7)*8;
  // sigma write targets for the V chunks (each short8 -> two short4 chunks)
  const int u0 = c0 >> 4, qd0 = (c0 & 15) >> 2;   // chunks qd0, qd0+1
  const int u1 = c1 >> 4, qd1 = (c1 & 15) >> 2;
  short8 rk[2], rv[2];
  // prefetch tile 0
  rk[0] = *(const short8*)(qkv + (size_t)(b*SEQ + r0)*3072 + 1024 + h*64 + c0);
  rk[1] = *(const short8*)(qkv + (size_t)(b*SEQ + r1)*3072 + 1024 + h*64 + c1);
  rv[0] = *(const short8*)(vt  + (size_t)(bh*64 + r0)*2048 + c0);
  rv[1] = *(const short8*)(vt  + (size_t)(bh*64 + r1)*2048 + c1);

  for (int it = 0; it < SEQ/64; it++){
    __syncthreads();
    *(short8*)&sK[r0][c0] = rk[0];
    *(short8*)&sK[r1][c1] = rk[1];
    { short4v lo = {rv[0][0],rv[0][1],rv[0][2],rv[0][3]};
      short4v hi = {rv[0][4],rv[0][5],rv[0][6],rv[0][7]};
      *(short4v*)&sVt[r0][qd0*16 + u0*4]     = lo;
      *(short4v*)&sVt[r0][(qd0+1)*16 + u0*4] = hi;
      lo = (short4v){rv[1][0],rv[1][1],rv[1][2],rv[1][3]};
      hi = (short4v){rv[1][4],rv[1][5],rv[1][6],rv[1][7]};
      *(short4v*)&sVt[r1][qd1*16 + u1*4]     = lo;
      *(short4v*)&sVt[r1][(qd1+1)*16 + u1*4] = hi;
    }
    __syncthreads();
    if (it + 1 < SEQ/64){              // prefetch next tile during compute
      int itn = (it + 1) * 64;
      rk[0] = *(const short8*)(qkv + (size_t)(b*SEQ + itn + r0)*3072 + 1024 + h*64 + c0);
      rk[1] = *(const short8*)(qkv + (size_t)(b*SEQ + itn + r1)*3072 + 1024 + h*64 + c1);
      rv[0] = *(const short8*)(vt  + (size_t)(bh*64 + r0)*2048 + itn + c0);
      rv[1] = *(const short8*)(vt  + (size_t)(bh*64 + r1)*2048 + itn + c1);
    }

    // S^T[kv][q]: A = K (m=kv), B = Q (n=q). C: row=kv local, col=q=l15.
    floatx4 sacc[4][2];
#pragma unroll
    for (int u=0;u<4;u++)
#pragma unroll
      for (int t=0;t<2;t++) sacc[u][t] = (floatx4){0.f,0.f,0.f,0.f};
#pragma unroll
    for (int ks=0;ks<2;ks++){
      short8 kf[4];
#pragma unroll
      for (int u=0;u<4;u++) kf[u] = *(const short8*)&sK[u*16 + l15][ks*32 + quad*8];
#pragma unroll
      for (int u=0;u<4;u++)
#pragma unroll
        for (int t=0;t<2;t++)
          sacc[u][t] = __builtin_amdgcn_mfma_f32_16x16x32_bf16(kf[u], qf[t][ks], sacc[u][t], 0,0,0);
    }

    // p = 2^s in-register; pack to f16 A-frags (k local = quad*4 + r)
    half4 pf[4][2];
#pragma unroll
    for (int t=0;t<2;t++){
#pragma unroll
      for (int u=0;u<4;u++){
        float p0 = __builtin_amdgcn_exp2f(sacc[u][t][0]);
        float p1 = __builtin_amdgcn_exp2f(sacc[u][t][1]);
        float p2 = __builtin_amdgcn_exp2f(sacc[u][t][2]);
        float p3 = __builtin_amdgcn_exp2f(sacc[u][t][3]);
        psum[t] += (p0+p1)+(p2+p3);
        union { pk2 p2v[2]; half4 h4; } cv;
        cv.p2v[0] = __builtin_amdgcn_cvt_pkrtz(p0,p1);
        cv.p2v[1] = __builtin_amdgcn_cvt_pkrtz(p2,p3);
        pf[u][t] = cv.h4;
      }
    }

    // O[q][dv] += P V : A = pf (m=q=l15), B = V[k=quad*4+j][n=dv=v*16+l15].
    // sigma layout: one b128 at col quad*16+h*8 yields vf[2h] | vf[2h+1].
#pragma unroll
    for (int v=0;v<4;v++){
      half4 vf[4];
#pragma unroll
      for (int hh=0;hh<2;hh++){
        short8 w = *(const short8*)&sVt[v*16 + l15][quad*16 + hh*8];
        union { short4v s; half4 h; } a, bb;
        a.s  = (short4v){w[0],w[1],w[2],w[3]};
        bb.s = (short4v){w[4],w[5],w[6],w[7]};
        vf[2*hh]   = a.h;
        vf[2*hh+1] = bb.h;
      }
#pragma unroll
      for (int t=0;t<2;t++)
#pragma unroll
        for (int u=0;u<4;u++)
          oacc[t][v] = MFMA16F16(pf[u][t], vf[u], oacc[t][v]);
    }
  }

  // final row-sum reduction: quads sharing l15 hold partials for q=l15
#pragma unroll
  for (int t=0;t<2;t++){
    float s = psum[t];
    s += __shfl_xor(s, 16);
    s += __shfl_xor(s, 32);
    psum[t] = s;
  }
  // epilogue: O rows are q local = quad*4+r; lsum for that q lives at lane q
#pragma unroll
  for (int t=0;t<2;t++){
#pragma unroll
    for (int r=0;r<4;r++){
      float inv = 1.0f / __shfl(psum[t], quad*4 + r);
      int tok = tok0 + wave*32 + t*16 + quad*4 + r;
#pragma unroll
      for (int v=0;v<4;v++)
        attn_out[(size_t)tok*1024 + h*64 + v*16 + l15] = f2b(oacc[t][v][r] * inv);
    }
  }
}

extern "C" void kernel_launch(void* const* d_in, const int* in_sizes, int n_in,
                              void* d_out, int out_size, void* d_ws, size_t ws_size,
                              hipStream_t stream)
{
  const float* x  = (const float*)d_in[0];
  const float* wq = (const float*)d_in[1];
  const float* bq = (const float*)d_in[2];
  const float* wk = (const float*)d_in[3];
  const float* bk = (const float*)d_in[4];
  const float* wv = (const float*)d_in[5];
  const float* bv = (const float*)d_in[6];
  const float* wo = (const float*)d_in[7];
  const float* bo = (const float*)d_in[8];
  float* out = (float*)d_out;

  char* ws = (char*)d_ws;
  unsigned short* wqkvT  = (unsigned short*)(ws);               // 3072x1024 bf16
  unsigned short* woT    = (unsigned short*)(ws + 6291456);     // 1024x1024 bf16
  float*          bqkv   = (float*)(ws + 8388608);              // 3072 f32
  unsigned short* xb     = (unsigned short*)(ws + 8400896);     // 8192x1024 bf16
  unsigned short* qkvbuf = (unsigned short*)(ws + 25178112);    // 8192x3072 bf16 (Q pre-scaled)
  unsigned short* vtbuf  = (unsigned short*)(ws + 75509760);    // 4096x2048 f16
  unsigned short* aobuf  = (unsigned short*)(ws + 92286976);    // 8192x1024 bf16

  hipMemsetAsync(out, 0, (size_t)out_size * sizeof(float), stream);
  prep_kernel<<<dim3(9228), 256, 0, stream>>>(x, wq, wk, wv, wo, bq, bk, bv,
                                              xb, wqkvT, woT, bqkv);
  gemm_bt_kernel<0,1><<<dim3(24, 64), 256, 0, stream>>>(xb, wqkvT, bqkv, qkvbuf,
                                                        8192, 3072, 1024, 1024);
  transpose_v_kernel<<<dim3(64, 32), 256, 0, stream>>>(qkvbuf, vtbuf);
  flash_attn_kernel<<<dim3(64, 16), 256, 0, stream>>>(qkvbuf, vtbuf, aobuf);
  gemm_bt_kernel<2,0><<<dim3(8, 64, 2), 256, 0, stream>>>(aobuf, woT, bo, out,
                                                          8192, 1024, 1024, 512);
}

// Round 8
// 292.380 us; speedup vs baseline: 1.1799x; 1.1799x over previous
//
#include <hip/hip_runtime.h>
#include <stdint.h>

typedef __attribute__((ext_vector_type(8))) short short8;
typedef __attribute__((ext_vector_type(4))) short short4v;
typedef __attribute__((ext_vector_type(4))) float floatx4;
typedef __attribute__((ext_vector_type(4))) _Float16 half4;
typedef __attribute__((ext_vector_type(2))) __fp16 pk2;

#define SEQ 2048
#define NTOK 8192
// 0.25 * log2(e): folds the 1/sqrt(H) quirk-scale and exp->exp2 into Q proj.
#define QSCALE 0.360673760222241f

#define MFMA16F16(a,b,c) __builtin_amdgcn_mfma_f32_16x16x16f16((a),(b),(c),0,0,0)

__device__ __forceinline__ float b2f(unsigned short u){
  union { unsigned int i; float f; } v; v.i = ((unsigned int)u) << 16; return v.f;
}
__device__ __forceinline__ unsigned short f2b(float f){
  union { float f; unsigned int i; } v; v.f = f;
  unsigned int r = v.i + 0x7fffu + ((v.i >> 16) & 1u);
  return (unsigned short)(r >> 16);
}
// async global->LDS, 16B per lane. Dest = wave-uniform base + lane*16.
__device__ __forceinline__ void async16(const unsigned short* g, unsigned short* l){
  __builtin_amdgcn_global_load_lds(
      (const __attribute__((address_space(1))) unsigned int*)g,
      (__attribute__((address_space(3))) unsigned int*)l, 16, 0, 0);
}

// ---------- fused prep: convert_x | transpose_w | bias_concat --------------
__global__ __launch_bounds__(256) void prep_kernel(
    const float* __restrict__ x,
    const float* __restrict__ wq, const float* __restrict__ wk,
    const float* __restrict__ wv, const float* __restrict__ wo,
    const float* __restrict__ bq, const float* __restrict__ bk,
    const float* __restrict__ bv,
    unsigned short* __restrict__ xb,
    unsigned short* __restrict__ wqkvT, unsigned short* __restrict__ woT,
    float* __restrict__ bqkv)
{
  __shared__ unsigned short lT[64][72];
  const int bid = blockIdx.x;
  const int tid = threadIdx.x;
  if (bid < 8192){
    int i = (bid*256 + tid)*4;
    float4 v = *(const float4*)(x + i);
    short4v o;
    o[0] = (short)f2b(v.x); o[1] = (short)f2b(v.y);
    o[2] = (short)f2b(v.z); o[3] = (short)f2b(v.w);
    *(short4v*)(xb + i) = o;
  } else if (bid < 9216){
    int idx = bid - 8192;
    int sel = idx >> 8, rest = idx & 255;
    const float* src = (sel==0)?wq:(sel==1)?wk:(sel==2)?wv:wo;
    unsigned short* dst = (sel<3) ? (wqkvT + (size_t)sel*1024*1024) : woT;
    int n0 = (rest & 15) * 64, k0 = (rest >> 4) * 64;
#pragma unroll
    for (int i=0;i<4;i++){
      int ch = tid + i*256;
      int r = ch>>4, c = (ch&15)*4;
      float4 v = *(const float4*)(src + (size_t)(k0+r)*1024 + n0 + c);
      lT[r][c+0] = f2b(v.x); lT[r][c+1] = f2b(v.y);
      lT[r][c+2] = f2b(v.z); lT[r][c+3] = f2b(v.w);
    }
    __syncthreads();
#pragma unroll
    for (int i=0;i<2;i++){
      int ch = tid + i*256;
      int rn = ch>>3, c = (ch&7)*8;
      short8 v;
#pragma unroll
      for (int j=0;j<8;j++) v[j] = (short)lT[c+j][rn];
      *(short8*)(dst + (size_t)(n0+rn)*1024 + k0 + c) = v;
    }
  } else {
    int i = (bid - 9216)*256 + tid;
    if (i < 3072){
      int sel = i >> 10, j = i & 1023;
      bqkv[i] = (sel==0)?bq[j]:(sel==1)?bk[j]:bv[j];
    }
  }
}

// ---------------- GEMM: C(MxN) = A(MxK) @ Bt(NxK)^T + bias ----------------
// MODE 1: f32 store. MODE 3: QKV fused — cols<1024 bf16*QSCALE, 1024..2047
// bf16, >=2048 (V) written f16 TRANSPOSED into Vt[(b*16+h)*64+dv][s]
// (fuses the old transpose_v kernel into the epilogue; V never hits qkvbuf).
template<int MODE>
__global__ __launch_bounds__(256) void gemm_bt_kernel(
    const unsigned short* __restrict__ A,
    const unsigned short* __restrict__ Bt,
    const float* __restrict__ bias,
    void* __restrict__ Cv,
    unsigned short* __restrict__ Vt,
    int M, int N, int K)
{
  __shared__ unsigned short lA[128*64];
  __shared__ unsigned short lB[128*64];
  const int tid  = threadIdx.x;
  const int lane = tid & 63;
  const int wave = tid >> 6;
  const int quad = lane >> 4;
  const int l15  = lane & 15;
  const int wR = (wave >> 1) * 64;
  const int wC = (wave & 1) * 64;
  const int rowB = blockIdx.y * 128;
  const int colB = blockIdx.x * 128;

  const int srow = wave*32 + (lane>>3);
  const int sc8  = (lane&7) ^ (lane>>3);
  const unsigned short* gA = A  + (size_t)(rowB + srow)*K + sc8*8;
  const unsigned short* gB = Bt + (size_t)(colB + srow)*K + sc8*8;
  unsigned short* lAw = lA + wave*32*64 + lane*8;
  unsigned short* lBw = lB + wave*32*64 + lane*8;

  floatx4 acc[4][4];
#pragma unroll
  for (int t=0;t<4;t++)
#pragma unroll
    for (int u=0;u<4;u++) acc[t][u] = (floatx4){0.f,0.f,0.f,0.f};

  for (int kt = 0; kt < K; kt += 64){
    __syncthreads();
#pragma unroll
    for (int i=0;i<4;i++){
      async16(gA + (size_t)i*8*K + kt, lAw + i*512);
      async16(gB + (size_t)i*8*K + kt, lBw + i*512);
    }
    __syncthreads();
#pragma unroll
    for (int ks=0; ks<2; ks++){
      const int cph = ((ks*4 + quad) ^ (l15 & 7)) * 8;
      short8 af[4], bf[4];
#pragma unroll
      for (int t=0;t<4;t++) af[t] = *(const short8*)&lA[(wR + t*16 + l15)*64 + cph];
#pragma unroll
      for (int u=0;u<4;u++) bf[u] = *(const short8*)&lB[(wC + u*16 + l15)*64 + cph];
#pragma unroll
      for (int t=0;t<4;t++)
#pragma unroll
        for (int u=0;u<4;u++)
          acc[t][u] = __builtin_amdgcn_mfma_f32_16x16x32_bf16(af[t], bf[u], acc[t][u], 0, 0, 0);
    }
  }
  // epilogue: C/D layout col = lane&15, row = quad*4 + r  [m89/m91 verified]
  if (MODE == 3 && colB >= 2048){
    // V block: transposed f16 store, 4 consecutive tokens per 8B chunk
#pragma unroll
    for (int u=0;u<4;u++){
      int col = colB + wC + u*16 + l15;
      float bval = bias[col];
      int vcol = col - 2048;
      int hh = vcol >> 6, dv = vcol & 63;
#pragma unroll
      for (int t=0;t<4;t++){
        int row0 = rowB + wR + t*16 + quad*4;       // token of acc[t][u][0]
        int bb = row0 >> 11, s = row0 & 2047;
        union { pk2 p[2]; short4v s4; } cv;
        cv.p[0] = __builtin_amdgcn_cvt_pkrtz(acc[t][u][0]+bval, acc[t][u][1]+bval);
        cv.p[1] = __builtin_amdgcn_cvt_pkrtz(acc[t][u][2]+bval, acc[t][u][3]+bval);
        *(short4v*)(Vt + ((size_t)(bb*16+hh)*64 + dv)*2048 + s) = cv.s4;
      }
    }
  } else {
#pragma unroll
    for (int u=0;u<4;u++){
      int col = colB + wC + u*16 + l15;
      float bval = bias[col];
      float scale = (MODE == 3 && col < 1024) ? QSCALE : 1.0f;
#pragma unroll
      for (int t=0;t<4;t++){
        int row0 = rowB + wR + t*16 + quad*4;
#pragma unroll
        for (int r=0;r<4;r++){
          float val = (acc[t][u][r] + bval) * scale;
          if (MODE == 1) ((float*)Cv)[(size_t)(row0 + r)*N + col] = val;
          else ((unsigned short*)Cv)[(size_t)(row0 + r)*N + col] = f2b(val);
        }
      }
    }
  }
}

// ---------------- flash attention forward, S^T formulation -----------------
// KV tile = 128 staged per barrier pair (two 64-row compute halves) — halves
// barrier count vs R6. Register prefetch of next tile during compute (the
// measured-best staging). Padded stride-72 LDS; V staged sigma-permuted so PV
// B-fragments are single b128 reads. P = exp2(S') (Q pre-scaled 0.25*log2e),
// row-sum deferred to one post-loop cross-quad reduction.
__global__ __launch_bounds__(256) void flash_attn_kernel(
    const unsigned short* __restrict__ qkv,
    const unsigned short* __restrict__ vt,      // f16 bits
    unsigned short* __restrict__ attn_out)      // bf16
{
  __shared__ unsigned short sK[2][64][72];      // bf16, [half][kv-local][dk]
  __shared__ unsigned short sVt[2][64][72];     // f16 bits, [half][dv][sigma(kv)]
  const int bh = blockIdx.x;
  const int b = bh >> 4, h = bh & 15;
  const int qt = blockIdx.y;
  const int tid = threadIdx.x;
  const int wave = tid >> 6;
  const int lane = tid & 63;
  const int quad = lane >> 4, l15 = lane & 15;
  const int tok0 = b*SEQ + qt*128;

  // Q B-fragments straight from global (n = q = l15, k contiguous)
  short8 qf[2][2];
#pragma unroll
  for (int t=0;t<2;t++)
#pragma unroll
    for (int ks=0;ks<2;ks++)
      qf[t][ks] = *(const short8*)(qkv + (size_t)(tok0 + wave*32 + t*16 + l15)*3072
                                   + h*64 + ks*32 + quad*8);

  floatx4 oacc[2][4];
  float psum[2] = {0.f, 0.f};
#pragma unroll
  for (int t=0;t<2;t++)
#pragma unroll
    for (int v=0;v<4;v++) oacc[t][v] = (floatx4){0.f,0.f,0.f,0.f};

  // staging geometry: 4 chunks per thread; chunk i covers half hf=i>>1,
  // row r (kv-local for K, dv for V), col c within the 64-wide half.
  int R[4], C[4], HF[4], U[4], QD[4];
#pragma unroll
  for (int i=0;i<4;i++){
    int chh = tid + (i&1)*256;
    R[i] = chh >> 3; C[i] = (chh & 7)*8; HF[i] = i >> 1;
    U[i] = C[i] >> 4; QD[i] = (C[i] & 15) >> 2;   // sigma targets (QD, QD+1)
  }
  short8 rk[4], rv[4];
  // prefetch tile 0
#pragma unroll
  for (int i=0;i<4;i++){
    rk[i] = *(const short8*)(qkv + (size_t)(b*SEQ + HF[i]*64 + R[i])*3072 + 1024 + h*64 + C[i]);
    rv[i] = *(const short8*)(vt  + (size_t)(bh*64 + R[i])*2048 + HF[i]*64 + C[i]);
  }

  for (int it = 0; it < SEQ/128; it++){
    __syncthreads();
#pragma unroll
    for (int i=0;i<4;i++){
      *(short8*)&sK[HF[i]][R[i]][C[i]] = rk[i];
      short4v lo = {rv[i][0],rv[i][1],rv[i][2],rv[i][3]};
      short4v hi = {rv[i][4],rv[i][5],rv[i][6],rv[i][7]};
      *(short4v*)&sVt[HF[i]][R[i]][QD[i]*16 + U[i]*4]     = lo;
      *(short4v*)&sVt[HF[i]][R[i]][(QD[i]+1)*16 + U[i]*4] = hi;
    }
    __syncthreads();
    if (it + 1 < SEQ/128){             // prefetch next 128-KV tile
      int nx = (it + 1) * 128;
#pragma unroll
      for (int i=0;i<4;i++){
        rk[i] = *(const short8*)(qkv + (size_t)(b*SEQ + nx + HF[i]*64 + R[i])*3072 + 1024 + h*64 + C[i]);
        rv[i] = *(const short8*)(vt  + (size_t)(bh*64 + R[i])*2048 + nx + HF[i]*64 + C[i]);
      }
    }

#pragma unroll
    for (int hf=0; hf<2; hf++){
      // S^T[kv][q]: A = K (m=kv), B = Q (n=q). C: row=kv local, col=q=l15.
      floatx4 sacc[4][2];
#pragma unroll
      for (int u=0;u<4;u++)
#pragma unroll
        for (int t=0;t<2;t++) sacc[u][t] = (floatx4){0.f,0.f,0.f,0.f};
#pragma unroll
      for (int ks=0;ks<2;ks++){
        short8 kf[4];
#pragma unroll
        for (int u=0;u<4;u++) kf[u] = *(const short8*)&sK[hf][u*16 + l15][ks*32 + quad*8];
#pragma unroll
        for (int u=0;u<4;u++)
#pragma unroll
          for (int t=0;t<2;t++)
            sacc[u][t] = __builtin_amdgcn_mfma_f32_16x16x32_bf16(kf[u], qf[t][ks], sacc[u][t], 0,0,0);
      }

      // p = 2^s in-register; pack to f16 A-frags (k local = quad*4 + r)
      half4 pf[4][2];
#pragma unroll
      for (int t=0;t<2;t++){
#pragma unroll
        for (int u=0;u<4;u++){
          float p0 = __builtin_amdgcn_exp2f(sacc[u][t][0]);
          float p1 = __builtin_amdgcn_exp2f(sacc[u][t][1]);
          float p2 = __builtin_amdgcn_exp2f(sacc[u][t][2]);
          float p3 = __builtin_amdgcn_exp2f(sacc[u][t][3]);
          psum[t] += (p0+p1)+(p2+p3);
          union { pk2 p2v[2]; half4 h4; } cv;
          cv.p2v[0] = __builtin_amdgcn_cvt_pkrtz(p0,p1);
          cv.p2v[1] = __builtin_amdgcn_cvt_pkrtz(p2,p3);
          pf[u][t] = cv.h4;
        }
      }

      // O[q][dv] += P V : sigma layout -> one b128 per vf pair
#pragma unroll
      for (int v=0;v<4;v++){
        half4 vf[4];
#pragma unroll
        for (int hh=0;hh<2;hh++){
          short8 w = *(const short8*)&sVt[hf][v*16 + l15][quad*16 + hh*8];
          union { short4v s; half4 h; } a, bb;
          a.s  = (short4v){w[0],w[1],w[2],w[3]};
          bb.s = (short4v){w[4],w[5],w[6],w[7]};
          vf[2*hh]   = a.h;
          vf[2*hh+1] = bb.h;
        }
#pragma unroll
        for (int t=0;t<2;t++)
#pragma unroll
          for (int u=0;u<4;u++)
            oacc[t][v] = MFMA16F16(pf[u][t], vf[u], oacc[t][v]);
      }
    }
  }

  // final row-sum reduction: quads sharing l15 hold partials for q=l15
#pragma unroll
  for (int t=0;t<2;t++){
    float s = psum[t];
    s += __shfl_xor(s, 16);
    s += __shfl_xor(s, 32);
    psum[t] = s;
  }
  // epilogue: O rows are q local = quad*4+r; lsum for that q lives at lane q
#pragma unroll
  for (int t=0;t<2;t++){
#pragma unroll
    for (int r=0;r<4;r++){
      float inv = 1.0f / __shfl(psum[t], quad*4 + r);
      int tok = tok0 + wave*32 + t*16 + quad*4 + r;
#pragma unroll
      for (int v=0;v<4;v++)
        attn_out[(size_t)tok*1024 + h*64 + v*16 + l15] = f2b(oacc[t][v][r] * inv);
    }
  }
}

extern "C" void kernel_launch(void* const* d_in, const int* in_sizes, int n_in,
                              void* d_out, int out_size, void* d_ws, size_t ws_size,
                              hipStream_t stream)
{
  const float* x  = (const float*)d_in[0];
  const float* wq = (const float*)d_in[1];
  const float* bq = (const float*)d_in[2];
  const float* wk = (const float*)d_in[3];
  const float* bk = (const float*)d_in[4];
  const float* wv = (const float*)d_in[5];
  const float* bv = (const float*)d_in[6];
  const float* wo = (const float*)d_in[7];
  const float* bo = (const float*)d_in[8];
  float* out = (float*)d_out;

  char* ws = (char*)d_ws;
  unsigned short* wqkvT  = (unsigned short*)(ws);               // 3072x1024 bf16
  unsigned short* woT    = (unsigned short*)(ws + 6291456);     // 1024x1024 bf16
  float*          bqkv   = (float*)(ws + 8388608);              // 3072 f32
  unsigned short* xb     = (unsigned short*)(ws + 8400896);     // 8192x1024 bf16
  unsigned short* qkvbuf = (unsigned short*)(ws + 25178112);    // 8192x3072 bf16 (V region unused)
  unsigned short* vtbuf  = (unsigned short*)(ws + 75509760);    // 4096x2048 f16
  unsigned short* aobuf  = (unsigned short*)(ws + 92286976);    // 8192x1024 bf16

  prep_kernel<<<dim3(9228), 256, 0, stream>>>(x, wq, wk, wv, wo, bq, bk, bv,
                                              xb, wqkvT, woT, bqkv);
  gemm_bt_kernel<3><<<dim3(24, 64), 256, 0, stream>>>(xb, wqkvT, bqkv, qkvbuf, vtbuf,
                                                      8192, 3072, 1024);
  flash_attn_kernel<<<dim3(64, 16), 256, 0, stream>>>(qkvbuf, vtbuf, aobuf);
  gemm_bt_kernel<1><<<dim3(8, 64), 256, 0, stream>>>(aobuf, woT, bo, out, nullptr,
                                                     8192, 1024, 1024);
}